// Round 6
// baseline (176.975 us; speedup 1.0000x reference)
//
#include <hip/hip_runtime.h>

#define NORIENT 8

// XCD-aware block swizzle: dispatch d -> XCD d%8 (round-robin). Remap so each
// XCD gets a contiguous chunk of logical tiles (halo rows shared in its L2).
__device__ __forceinline__ unsigned xcd_swz(unsigned bid, unsigned nwg) {
    unsigned chunk = nwg >> 3;
    return (nwg & 7u) ? bid : (bid & 7u) * chunk + (bid >> 3);
}

// ---------------- forward: stride-2 5x5 conv, 1 -> 8 channels ----------------
// Thread owns output rows {2*oyb, 2*oyb+1} x cols {4*oxb..4*oxb+3}, all 8 ch.
// Patch rows 4*oyb-2..+4 (7), cols 8*oxb-2..8*oxb+8 (11):
// float2(edge) + float4 + float4 + scalar(edge) = 4 VMEM, 44 B per row.
// __launch_bounds__(256,4): 128-VGPR budget so acc[8][2][4] stays in registers
// (R5 lesson: default compiler target is 64 VGPR / 8 waves -> spills to scratch,
// seen as WRITE_SIZE 2.5x output and FETCH 4x input).
__global__ __launch_bounds__(256, 4)
void fwd_conv_kernel(const float* __restrict__ in, long in_img_stride,
                     const float* __restrict__ filt,
                     float* __restrict__ out,
                     int H, int W, int OH, int OW, int N) {
    int OHB = OH >> 1, OWB = OW >> 2;
    unsigned sb = xcd_swz(blockIdx.x, gridDim.x);
    long idx = (long)sb * blockDim.x + threadIdx.x;
    long total = (long)N * OHB * OWB;
    if (idx >= total) return;
    int oxb = (int)(idx % OWB);
    long t = idx / OWB;
    int oyb = (int)(t % OHB);
    int n = (int)(t / OHB);

    const float* __restrict__ ip = in + (long)n * in_img_stride;
    int x0 = 8 * oxb;                       // patch col k maps to input col x0-2+k
    bool um = oxb > 0, up = (x0 + 8) < W;
    int bA = um ? x0 - 2 : 0;               // float2 covering cols x0-2, x0-1 (8B-aligned)
    int bD = up ? x0 + 8 : W - 1;           // scalar col x0+8

    float acc[NORIENT][2][4];
#pragma unroll
    for (int c = 0; c < NORIENT; ++c)
#pragma unroll
        for (int dy = 0; dy < 2; ++dy)
#pragma unroll
            for (int dx = 0; dx < 4; ++dx) acc[c][dy][dx] = 0.f;

#pragma unroll
    for (int r = 0; r < 7; ++r) {
        int y = 4 * oyb - 2 + r;
        bool vy = (y >= 0) & (y < H);
        int yc = vy ? y : (y < 0 ? 0 : H - 1);
        float rm = vy ? 1.f : 0.f;
        const float* __restrict__ row = ip + (long)yc * W;
        float2 A = *(const float2*)(row + bA);
        float4 B = *(const float4*)(row + x0);
        float4 C = *(const float4*)(row + x0 + 4);
        float  D = row[bD];
        float mL = um ? rm : 0.f, mR = up ? rm : 0.f;
        float P[11];
        P[0] = A.x * mL; P[1] = A.y * mL;
        P[2] = B.x * rm; P[3] = B.y * rm; P[4] = B.z * rm; P[5] = B.w * rm;
        P[6] = C.x * rm; P[7] = C.y * rm; P[8] = C.z * rm; P[9] = C.w * rm;
        P[10] = D * mR;

#pragma unroll
        for (int dy = 0; dy < 2; ++dy) {
            int i = r - 2 * dy;
            if (i < 0 || i > 4) continue;   // compile-time
#pragma unroll
            for (int j = 0; j < 5; ++j) {
#pragma unroll
                for (int c = 0; c < NORIENT; ++c) {
                    float wv = filt[c * 25 + i * 5 + j];   // wave-uniform -> s_load
#pragma unroll
                    for (int dx = 0; dx < 4; ++dx)
                        acc[c][dy][dx] = fmaf(P[2 * dx + j], wv, acc[c][dy][dx]);
                }
            }
        }
    }

    long cs = (long)OH * OW;
    long ob0 = (long)n * NORIENT * cs + (long)(2 * oyb) * OW + 4 * oxb;
#pragma unroll
    for (int c = 0; c < NORIENT; ++c) {
#pragma unroll
        for (int dy = 0; dy < 2; ++dy) {
            *(float4*)(out + ob0 + (long)c * cs + (long)dy * OW) =
                make_float4(acc[c][dy][0], acc[c][dy][1], acc[c][dy][2], acc[c][dy][3]);
        }
    }
}

// ---------------- inverse: transposed conv, 8 -> 1 channel, stride 2 ----------------
// Thread owns a 2x2 block of coefficient sites (p in {2a0,2a0+1}, q in {2b0,2b0+1})
// and computes the 4x4 output block (rows 4a0..+3, cols 4b0..+3).
// Per channel: 4 patch rows x 3 aligned float2 loads (12 VMEM). Stores are 4x
// float4, lane-contiguous per instruction (byte offset 16*lane) — the pattern
// R2 proved keeps WRITE_SIZE == output size (R3's strided float4s caused 10x RMW).
__global__ __launch_bounds__(256, 4)
void inv_tconv_kernel(const float* __restrict__ rec, long rec_img_stride,
                      const float* __restrict__ coef,
                      const float* __restrict__ filt,
                      float* __restrict__ out,
                      int h, int w, int N) {
    int h2 = h >> 1, w2 = w >> 1;
    unsigned sb = xcd_swz(blockIdx.x, gridDim.x);
    long idx = (long)sb * blockDim.x + threadIdx.x;
    long total = (long)N * h2 * w2;
    if (idx >= total) return;
    int b0 = (int)(idx % w2);
    long t = idx / w2;
    int a0 = (int)(t % h2);
    int n = (int)(t / h2);

    const float* __restrict__ rp = rec + (long)n * rec_img_stride;
    const float* __restrict__ cp = coef + (long)n * (long)NORIENT * h * w;
    int cs = h * w;

    bool fmv = a0 > 0, fpv = a0 < h2 - 1;
    bool um = b0 > 0, up = b0 < w2 - 1;
    float fm = fmv ? 1.f : 0.f, fp_ = fpv ? 1.f : 0.f;
    int r0 = (fmv ? 2 * a0 - 1 : 0) * w;
    int r1 = (2 * a0) * w;
    int r2 = (2 * a0 + 1) * w;
    int r3 = (fpv ? 2 * a0 + 2 : 2 * a0 + 1) * w;
    int cL = um ? 2 * b0 - 2 : 0;
    int cM = 2 * b0;
    int cR = up ? 2 * b0 + 2 : 0;

    float acc[2][2][2][2];  // [sr][sc][dy][dx]
#pragma unroll
    for (int i = 0; i < 2; ++i)
#pragma unroll
        for (int j = 0; j < 2; ++j)
#pragma unroll
            for (int k = 0; k < 2; ++k)
#pragma unroll
                for (int l = 0; l < 2; ++l) acc[i][j][k][l] = 0.f;

    auto do_channel = [&](const float* __restrict__ src, const float* __restrict__ F) {
        float P[4][4];
        const int ro[4] = {r0, r1, r2, r3};
        const float rm[4] = {fm, 1.f, 1.f, fp_};
#pragma unroll
        for (int r = 0; r < 4; ++r) {
            const float* base = src + ro[r];
            float2 L = *(const float2*)(base + cL);
            float2 M = *(const float2*)(base + cM);
            float2 R = *(const float2*)(base + cR);
            float mask = rm[r];
            P[r][0] = (um ? L.y : 0.f) * mask;
            P[r][1] = M.x * mask;
            P[r][2] = M.y * mask;
            P[r][3] = (up ? R.x : 0.f) * mask;
        }
#pragma unroll
        for (int a = 0; a < 3; ++a) {
#pragma unroll
            for (int b = 0; b < 3; ++b) {
                float w00 = F[(4 - 2 * a) * 5 + (4 - 2 * b)];
                float w01 = (b >= 1) ? F[(4 - 2 * a) * 5 + (5 - 2 * b)] : 0.f;
                float w10 = (a >= 1) ? F[(5 - 2 * a) * 5 + (4 - 2 * b)] : 0.f;
                float w11 = (a >= 1 && b >= 1) ? F[(5 - 2 * a) * 5 + (5 - 2 * b)] : 0.f;
#pragma unroll
                for (int sr = 0; sr < 2; ++sr) {
#pragma unroll
                    for (int sc = 0; sc < 2; ++sc) {
                        float pv = P[sr + a][sc + b];
                        acc[sr][sc][0][0] = fmaf(pv, w00, acc[sr][sc][0][0]);
                        if (b >= 1) acc[sr][sc][0][1] = fmaf(pv, w01, acc[sr][sc][0][1]);
                        if (a >= 1) acc[sr][sc][1][0] = fmaf(pv, w10, acc[sr][sc][1][0]);
                        if (a >= 1 && b >= 1)
                                    acc[sr][sc][1][1] = fmaf(pv, w11, acc[sr][sc][1][1]);
                    }
                }
            }
        }
    };

    do_channel(rp, filt);
#pragma unroll
    for (int c = 1; c < NORIENT; ++c)
        do_channel(cp + (long)c * cs, filt + c * 25);

    int OW = w << 1;
    long ob = (long)n * 4 * (long)cs + (long)(4 * a0) * OW + 4 * b0;
    *(float4*)(out + ob)          = make_float4(acc[0][0][0][0], acc[0][0][0][1],
                                                acc[0][1][0][0], acc[0][1][0][1]);
    *(float4*)(out + ob + OW)     = make_float4(acc[0][0][1][0], acc[0][0][1][1],
                                                acc[0][1][1][0], acc[0][1][1][1]);
    *(float4*)(out + ob + 2 * OW) = make_float4(acc[1][0][0][0], acc[1][0][0][1],
                                                acc[1][1][0][0], acc[1][1][0][1]);
    *(float4*)(out + ob + 3 * OW) = make_float4(acc[1][0][1][0], acc[1][0][1][1],
                                                acc[1][1][1][0], acc[1][1][1][1]);
}

extern "C" void kernel_launch(void* const* d_in, const int* in_sizes, int n_in,
                              void* d_out, int out_size, void* d_ws, size_t ws_size,
                              hipStream_t stream) {
    const float* x     = (const float*)d_in[0];
    const float* fwd_f = (const float*)d_in[1];
    const float* inv_f = (const float*)d_in[2];
    float* out = (float*)d_out;
    float* ws  = (float*)d_ws;

    const int N = 32;

    // workspace layout (floats) — all offsets multiples of 4 -> 16B aligned
    float* l4 = ws;                  // 32*8*256*256 = 16,777,216
    float* l3 = l4 + 16777216;       // 32*8*128*128 =  4,194,304
    float* l2 = l3 + 4194304;        // 32*8*64*64   =  1,048,576
    float* l1 = l2 + 1048576;        // 32*8*32*32   =    262,144
    float* r1 = l1 + 262144;         // 32*64*64     =    131,072
    float* r2 = r1 + 131072;         // 32*128*128   =    524,288
    float* r3 = r2 + 524288;         // 32*256*256   =  2,097,152

    dim3 blk(256);
    auto nblocks = [](long total) { return dim3((unsigned)((total + 255) / 256)); };

    // ---- forward transform (threads = N * OH/2 * OW/4) ----
    fwd_conv_kernel<<<nblocks(32L * 128 * 64), blk, 0, stream>>>(
        x, 512L * 512, fwd_f, l4, 512, 512, 256, 256, N);
    fwd_conv_kernel<<<nblocks(32L * 64 * 32), blk, 0, stream>>>(
        l4, 8L * 256 * 256, fwd_f, l3, 256, 256, 128, 128, N);
    fwd_conv_kernel<<<nblocks(32L * 32 * 16), blk, 0, stream>>>(
        l3, 8L * 128 * 128, fwd_f, l2, 128, 128, 64, 64, N);
    fwd_conv_kernel<<<nblocks(32L * 16 * 8), blk, 0, stream>>>(
        l2, 8L * 64 * 64, fwd_f, l1, 64, 64, 32, 32, N);

    // ---- inverse transform (threads = N * h/2 * w/2) ----
    inv_tconv_kernel<<<nblocks(32L * 16 * 16), blk, 0, stream>>>(
        l1, 8L * 32 * 32, l1, inv_f, r1, 32, 32, N);
    inv_tconv_kernel<<<nblocks(32L * 32 * 32), blk, 0, stream>>>(
        r1, 64L * 64, l2, inv_f, r2, 64, 64, N);
    inv_tconv_kernel<<<nblocks(32L * 64 * 64), blk, 0, stream>>>(
        r2, 128L * 128, l3, inv_f, r3, 128, 128, N);
    inv_tconv_kernel<<<nblocks(32L * 128 * 128), blk, 0, stream>>>(
        r3, 256L * 256, l4, inv_f, out, 256, 256, N);
}

// Round 7
// 98.389 us; speedup vs baseline: 1.7987x; 1.7987x over previous
//
#include <hip/hip_runtime.h>

#define NORIENT 8

// XCD-aware block swizzle: dispatch d -> XCD d%8 (round-robin). Remap so each
// XCD gets a contiguous chunk of logical tiles (halo rows shared in its L2).
__device__ __forceinline__ unsigned xcd_swz(unsigned bid, unsigned nwg) {
    unsigned chunk = nwg >> 3;
    return (nwg & 7u) ? bid : (bid & 7u) * chunk + (bid >> 3);
}

// ---------------- forward: stride-2 5x5 conv, 1 -> 8 channels ----------------
// Thread owns output rows {2*oy2, 2*oy2+1} x cols {2*ox2, 2*ox2+1}, all 8 ch.
// (R4-proven register budget: acc[8][2][2]=32 floats, VGPR<=64, no spill.)
// Patch rows 4*oy2-2..+4 (7), cols 4*ox2-2..4*ox2+4 (7):
// float2(aligned) + float4(aligned) + scalar = 3 VMEM, 28 B per row (vs R4's
// 7 scalar loads/row). R5/R6 lesson: >64 live regs => scratch spills (WRITE
// 2.4x output); compiler won't exceed 64 VGPR regardless of launch_bounds.
__global__ void fwd_conv_kernel(const float* __restrict__ in, long in_img_stride,
                                const float* __restrict__ filt,
                                float* __restrict__ out,
                                int H, int W, int OH, int OW, int N) {
    int OH2 = OH >> 1, OW2 = OW >> 1;
    unsigned sb = xcd_swz(blockIdx.x, gridDim.x);
    long idx = (long)sb * blockDim.x + threadIdx.x;
    long total = (long)N * OH2 * OW2;
    if (idx >= total) return;
    int ox2 = (int)(idx % OW2);
    long t = idx / OW2;
    int oy2 = (int)(t % OH2);
    int n = (int)(t / OH2);

    const float* __restrict__ ip = in + (long)n * in_img_stride;
    int x0 = 4 * ox2;                      // patch col k maps to input col x0-2+k
    bool um = ox2 > 0, up = (x0 + 4) < W;
    int bA = um ? x0 - 2 : 0;              // float2: cols x0-2, x0-1 (8B aligned)
    int bD = up ? x0 + 4 : W - 1;          // scalar: col x0+4

    float acc[NORIENT][2][2];
#pragma unroll
    for (int c = 0; c < NORIENT; ++c)
#pragma unroll
        for (int dy = 0; dy < 2; ++dy) {
            acc[c][dy][0] = 0.f;
            acc[c][dy][1] = 0.f;
        }

#pragma unroll
    for (int r = 0; r < 7; ++r) {
        int y = 4 * oy2 - 2 + r;
        bool vy = (y >= 0) & (y < H);
        int yc = vy ? y : (y < 0 ? 0 : H - 1);
        float rm = vy ? 1.f : 0.f;
        const float* __restrict__ row = ip + (long)yc * W;
        float2 A = *(const float2*)(row + bA);
        float4 B = *(const float4*)(row + x0);
        float  D = row[bD];
        float mL = um ? rm : 0.f, mR = up ? rm : 0.f;
        float P[7];
        P[0] = A.x * mL; P[1] = A.y * mL;
        P[2] = B.x * rm; P[3] = B.y * rm; P[4] = B.z * rm; P[5] = B.w * rm;
        P[6] = D * mR;

#pragma unroll
        for (int dy = 0; dy < 2; ++dy) {
            int i = r - 2 * dy;
            if (i < 0 || i > 4) continue;   // compile-time
#pragma unroll
            for (int j = 0; j < 5; ++j) {
#pragma unroll
                for (int c = 0; c < NORIENT; ++c) {
                    float wv = filt[c * 25 + i * 5 + j];   // wave-uniform -> s_load
                    acc[c][dy][0] = fmaf(P[j],     wv, acc[c][dy][0]);
                    acc[c][dy][1] = fmaf(P[j + 2], wv, acc[c][dy][1]);
                }
            }
        }
    }

    long cs = (long)OH * OW;
    long ob0 = (long)n * NORIENT * cs + (long)(2 * oy2) * OW + 2 * ox2;
#pragma unroll
    for (int c = 0; c < NORIENT; ++c) {
#pragma unroll
        for (int dy = 0; dy < 2; ++dy) {
            *(float2*)(out + ob0 + (long)c * cs + (long)dy * OW) =
                make_float2(acc[c][dy][0], acc[c][dy][1]);
        }
    }
}

// ---------------- inverse: transposed conv, 8 -> 1 channel, stride 2 ----------------
// Thread owns a 2x2 block of coefficient sites (p in {2a0,2a0+1}, q in {2b0,2b0+1})
// and computes the 4x4 output block (rows 4a0..+3, cols 4b0..+3).
// Per channel: 4 patch rows x 3 aligned float2 loads (12 VMEM). Stores are 4x
// float4, lane-contiguous per instruction (byte offset 16*lane) — the pattern
// R2 proved keeps WRITE_SIZE == output size (R3's strided float4s caused 10x RMW).
// Exact R4 version (64 VGPR, clean counters).
__global__ void inv_tconv_kernel(const float* __restrict__ rec, long rec_img_stride,
                                 const float* __restrict__ coef,
                                 const float* __restrict__ filt,
                                 float* __restrict__ out,
                                 int h, int w, int N) {
    int h2 = h >> 1, w2 = w >> 1;
    unsigned sb = xcd_swz(blockIdx.x, gridDim.x);
    long idx = (long)sb * blockDim.x + threadIdx.x;
    long total = (long)N * h2 * w2;
    if (idx >= total) return;
    int b0 = (int)(idx % w2);
    long t = idx / w2;
    int a0 = (int)(t % h2);
    int n = (int)(t / h2);

    const float* __restrict__ rp = rec + (long)n * rec_img_stride;
    const float* __restrict__ cp = coef + (long)n * (long)NORIENT * h * w;
    int cs = h * w;

    bool fmv = a0 > 0, fpv = a0 < h2 - 1;
    bool um = b0 > 0, up = b0 < w2 - 1;
    float fm = fmv ? 1.f : 0.f, fp_ = fpv ? 1.f : 0.f;
    int r0 = (fmv ? 2 * a0 - 1 : 0) * w;
    int r1 = (2 * a0) * w;
    int r2 = (2 * a0 + 1) * w;
    int r3 = (fpv ? 2 * a0 + 2 : 2 * a0 + 1) * w;
    int cL = um ? 2 * b0 - 2 : 0;
    int cM = 2 * b0;
    int cR = up ? 2 * b0 + 2 : 0;

    float acc[2][2][2][2];  // [sr][sc][dy][dx]
#pragma unroll
    for (int i = 0; i < 2; ++i)
#pragma unroll
        for (int j = 0; j < 2; ++j)
#pragma unroll
            for (int k = 0; k < 2; ++k)
#pragma unroll
                for (int l = 0; l < 2; ++l) acc[i][j][k][l] = 0.f;

    auto do_channel = [&](const float* __restrict__ src, const float* __restrict__ F) {
        float P[4][4];
        const int ro[4] = {r0, r1, r2, r3};
        const float rm[4] = {fm, 1.f, 1.f, fp_};
#pragma unroll
        for (int r = 0; r < 4; ++r) {
            const float* base = src + ro[r];
            float2 L = *(const float2*)(base + cL);
            float2 M = *(const float2*)(base + cM);
            float2 R = *(const float2*)(base + cR);
            float mask = rm[r];
            P[r][0] = (um ? L.y : 0.f) * mask;
            P[r][1] = M.x * mask;
            P[r][2] = M.y * mask;
            P[r][3] = (up ? R.x : 0.f) * mask;
        }
#pragma unroll
        for (int a = 0; a < 3; ++a) {
#pragma unroll
            for (int b = 0; b < 3; ++b) {
                float w00 = F[(4 - 2 * a) * 5 + (4 - 2 * b)];
                float w01 = (b >= 1) ? F[(4 - 2 * a) * 5 + (5 - 2 * b)] : 0.f;
                float w10 = (a >= 1) ? F[(5 - 2 * a) * 5 + (4 - 2 * b)] : 0.f;
                float w11 = (a >= 1 && b >= 1) ? F[(5 - 2 * a) * 5 + (5 - 2 * b)] : 0.f;
#pragma unroll
                for (int sr = 0; sr < 2; ++sr) {
#pragma unroll
                    for (int sc = 0; sc < 2; ++sc) {
                        float pv = P[sr + a][sc + b];
                        acc[sr][sc][0][0] = fmaf(pv, w00, acc[sr][sc][0][0]);
                        if (b >= 1) acc[sr][sc][0][1] = fmaf(pv, w01, acc[sr][sc][0][1]);
                        if (a >= 1) acc[sr][sc][1][0] = fmaf(pv, w10, acc[sr][sc][1][0]);
                        if (a >= 1 && b >= 1)
                                    acc[sr][sc][1][1] = fmaf(pv, w11, acc[sr][sc][1][1]);
                    }
                }
            }
        }
    };

    do_channel(rp, filt);
#pragma unroll
    for (int c = 1; c < NORIENT; ++c)
        do_channel(cp + (long)c * cs, filt + c * 25);

    int OW = w << 1;
    long ob = (long)n * 4 * (long)cs + (long)(4 * a0) * OW + 4 * b0;
    *(float4*)(out + ob)          = make_float4(acc[0][0][0][0], acc[0][0][0][1],
                                                acc[0][1][0][0], acc[0][1][0][1]);
    *(float4*)(out + ob + OW)     = make_float4(acc[0][0][1][0], acc[0][0][1][1],
                                                acc[0][1][1][0], acc[0][1][1][1]);
    *(float4*)(out + ob + 2 * OW) = make_float4(acc[1][0][0][0], acc[1][0][0][1],
                                                acc[1][1][0][0], acc[1][1][0][1]);
    *(float4*)(out + ob + 3 * OW) = make_float4(acc[1][0][1][0], acc[1][0][1][1],
                                                acc[1][1][1][0], acc[1][1][1][1]);
}

extern "C" void kernel_launch(void* const* d_in, const int* in_sizes, int n_in,
                              void* d_out, int out_size, void* d_ws, size_t ws_size,
                              hipStream_t stream) {
    const float* x     = (const float*)d_in[0];
    const float* fwd_f = (const float*)d_in[1];
    const float* inv_f = (const float*)d_in[2];
    float* out = (float*)d_out;
    float* ws  = (float*)d_ws;

    const int N = 32;

    // workspace layout (floats) — all offsets multiples of 4 -> 16B aligned
    float* l4 = ws;                  // 32*8*256*256 = 16,777,216
    float* l3 = l4 + 16777216;       // 32*8*128*128 =  4,194,304
    float* l2 = l3 + 4194304;        // 32*8*64*64   =  1,048,576
    float* l1 = l2 + 1048576;        // 32*8*32*32   =    262,144
    float* r1 = l1 + 262144;         // 32*64*64     =    131,072
    float* r2 = r1 + 131072;         // 32*128*128   =    524,288
    float* r3 = r2 + 524288;         // 32*256*256   =  2,097,152

    dim3 blk(256);
    auto nblocks = [](long total) { return dim3((unsigned)((total + 255) / 256)); };

    // ---- forward transform (threads = N * OH/2 * OW/2) ----
    fwd_conv_kernel<<<nblocks(32L * 128 * 128), blk, 0, stream>>>(
        x, 512L * 512, fwd_f, l4, 512, 512, 256, 256, N);
    fwd_conv_kernel<<<nblocks(32L * 64 * 64), blk, 0, stream>>>(
        l4, 8L * 256 * 256, fwd_f, l3, 256, 256, 128, 128, N);
    fwd_conv_kernel<<<nblocks(32L * 32 * 32), blk, 0, stream>>>(
        l3, 8L * 128 * 128, fwd_f, l2, 128, 128, 64, 64, N);
    fwd_conv_kernel<<<nblocks(32L * 16 * 16), blk, 0, stream>>>(
        l2, 8L * 64 * 64, fwd_f, l1, 64, 64, 32, 32, N);

    // ---- inverse transform (threads = N * h/2 * w/2) ----
    inv_tconv_kernel<<<nblocks(32L * 16 * 16), blk, 0, stream>>>(
        l1, 8L * 32 * 32, l1, inv_f, r1, 32, 32, N);
    inv_tconv_kernel<<<nblocks(32L * 32 * 32), blk, 0, stream>>>(
        r1, 64L * 64, l2, inv_f, r2, 64, 64, N);
    inv_tconv_kernel<<<nblocks(32L * 64 * 64), blk, 0, stream>>>(
        r2, 128L * 128, l3, inv_f, r3, 128, 128, N);
    inv_tconv_kernel<<<nblocks(32L * 128 * 128), blk, 0, stream>>>(
        r3, 256L * 256, l4, inv_f, out, 256, 256, N);
}